// Round 1
// baseline (64.493 us; speedup 1.0000x reference)
//
#include <hip/hip_runtime.h>

#define SIGMA_C 1e-4f
#define EPS_C   1e-12f

struct V3 { float x, y, z; };

__device__ __forceinline__ V3 v3sub(V3 a, V3 b) { return {a.x - b.x, a.y - b.y, a.z - b.z}; }
__device__ __forceinline__ float v3dot(V3 a, V3 b) { return a.x * b.x + a.y * b.y + a.z * b.z; }
__device__ __forceinline__ V3 v3cross(V3 a, V3 b) {
    return {a.y * b.z - a.z * b.y,
            a.z * b.x - a.x * b.z,
            a.x * b.y - a.y * b.x};
}

// centroid c, unit normal n, circum-radius r (max vertex distance to centroid)
__device__ __forceinline__ void tri_frame(const V3 v[3], V3& c, V3& n, float& r) {
    const float third = 1.0f / 3.0f;
    c.x = (v[0].x + v[1].x + v[2].x) * third;
    c.y = (v[0].y + v[1].y + v[2].y) * third;
    c.z = (v[0].z + v[1].z + v[2].z) * third;
    V3 e1 = v3sub(v[1], v[0]);
    V3 e2 = v3sub(v[2], v[0]);
    n = v3cross(e1, e2);
    float nn = sqrtf(v3dot(n, n));
    float inv = 1.0f / fmaxf(nn, EPS_C);
    n.x *= inv; n.y *= inv; n.z *= inv;
    V3 d0 = v3sub(v[0], c), d1 = v3sub(v[1], c), d2 = v3sub(v[2], c);
    float m = fmaxf(fmaxf(v3dot(d0, d0), v3dot(d1, d1)), v3dot(d2, d2));
    r = sqrtf(m);
}

// sum over the 3 points of psi^2, cone given by (c, n, r)
__device__ __forceinline__ float cone_psi2(const V3 p[3], V3 c, V3 n, float r) {
    float inv_r = 1.0f / fmaxf(r, EPS_C);
    float s = 0.0f;
#pragma unroll
    for (int i = 0; i < 3; ++i) {
        V3 u = v3sub(p[i], c);
        float h = v3dot(u, n);
        V3 w = {u.x - h * n.x, u.y - h * n.y, u.z - h * n.z};
        float rho = sqrtf(v3dot(w, w));
        float radial = fmaxf(1.0f - rho * inv_r, 0.0f);
        float axial = fmaxf(SIGMA_C - h, 0.0f);   // PENALIZE_OUTSIDE = True
        float psi = radial * axial;
        s += psi * psi;
    }
    return s;
}

__global__ void interp_zero(float* out, int n) {
    int i = blockIdx.x * blockDim.x + threadIdx.x;
    if (i < n) out[i] = 0.0f;
}

__global__ void Interpenetration_71949292142878_kernel(
        const float* __restrict__ verts,   // [B, V, 3]
        const int*   __restrict__ faces,   // [F, 3]
        const int2*  __restrict__ coll,    // [B, C] pairs
        float* __restrict__ out,           // [B]
        int V, int C) {
    const int b = blockIdx.y;
    const float* vb = verts + (size_t)b * (size_t)V * 3u;
    const int2* cb = coll + (size_t)b * (size_t)C;

    float acc = 0.0f;
    const int stride = gridDim.x * blockDim.x;
    for (int c = blockIdx.x * blockDim.x + threadIdx.x; c < C; c += stride) {
        int2 idx = cb[c];
        if ((idx.x | idx.y) >= 0) {   // both indices non-negative
            const int* fr = faces + 3 * idx.x;
            const int* fi = faces + 3 * idx.y;
            V3 tr[3], ti[3];
#pragma unroll
            for (int j = 0; j < 3; ++j) {
                int vr = fr[j];
                tr[j] = {vb[3 * vr + 0], vb[3 * vr + 1], vb[3 * vr + 2]};
                int vi = fi[j];
                ti[j] = {vb[3 * vi + 0], vb[3 * vi + 1], vb[3 * vi + 2]};
            }
            V3 rc, rn; float rr;
            tri_frame(tr, rc, rn, rr);
            V3 ic, in_; float ir;
            tri_frame(ti, ic, in_, ir);
            acc += cone_psi2(ti, rc, rn, rr);   // psi_i: intruder verts vs recv cone
            acc += cone_psi2(tr, ic, in_, ir);  // psi_r: recv verts vs intruder cone
        }
    }

    // wave (64) shuffle reduction
#pragma unroll
    for (int off = 32; off > 0; off >>= 1)
        acc += __shfl_down(acc, off, 64);

    __shared__ float red[16];
    int lane = threadIdx.x & 63;
    int wid  = threadIdx.x >> 6;
    if (lane == 0) red[wid] = acc;
    __syncthreads();
    if (threadIdx.x == 0) {
        float s = 0.0f;
        int nw = blockDim.x >> 6;
        for (int i = 0; i < nw; ++i) s += red[i];
        atomicAdd(&out[b], s);
    }
}

extern "C" void kernel_launch(void* const* d_in, const int* in_sizes, int n_in,
                              void* d_out, int out_size, void* d_ws, size_t ws_size,
                              hipStream_t stream) {
    const float* verts = (const float*)d_in[0];
    const int*   faces = (const int*)d_in[1];
    const int2*  coll  = (const int2*)d_in[2];
    float* out = (float*)d_out;

    const int B = out_size;                       // 8
    const int V = in_sizes[0] / (3 * B);          // 10475
    const int C = in_sizes[2] / (2 * B);          // 262144

    interp_zero<<<1, 64, 0, stream>>>(out, B);

    dim3 block(256);
    dim3 grid(256, B);
    Interpenetration_71949292142878_kernel<<<grid, block, 0, stream>>>(
        verts, faces, coll, out, V, C);
}